// Round 5
// baseline (126.908 us; speedup 1.0000x reference)
//
#include <hip/hip_runtime.h>

typedef __bf16 bf16x8 __attribute__((ext_vector_type(8)));
typedef float f32x4 __attribute__((ext_vector_type(4)));

#define DEV static __device__ __forceinline__

DEV unsigned short f2b(float f){
    unsigned int u = __float_as_uint(f);
    u += 0x7fffu + ((u >> 16) & 1u);
    return (unsigned short)(u >> 16);
}
DEV float b2f(unsigned short h){ return __uint_as_float(((unsigned int)h) << 16); }
DEV float gelu_f(float x){ return 0.5f * x * (1.0f + erff(x * 0.7071067811865476f)); }

// async global->LDS, 16B per lane. LDS dest must be linear in lane order.
DEV void gload16(const unsigned short* g, unsigned short* l){
    __builtin_amdgcn_global_load_lds(
        (const __attribute__((address_space(1))) void*)g,
        (__attribute__((address_space(3))) void*)l, 16, 0, 0);
}

// ---------------------------------------------------------------- constants
static constexpr int NROW = 8192;   // B*D*H*W = 2*16*16*16
static constexpr int C    = 256;
static constexpr int F    = 1024;
static constexpr float ATT_SCALE = 0.17677669529663688f;   // 1/sqrt(32)

// ---------------------------------------------------------------- prep + LN1
// Blocks 0..3074: transpose + bf16-convert weights (Wq/bq pre-scaled).
// Blocks 3075..5122: vectorized LN1 of x (also emits bf16 copy of x).
__global__ __launch_bounds__(256)
void prep_ln_kernel(const float* __restrict__ Wq, const float* __restrict__ Wk,
                    const float* __restrict__ Wv, const float* __restrict__ Wo,
                    const float* __restrict__ W1, const float* __restrict__ W2,
                    const float* __restrict__ bq, const float* __restrict__ bk,
                    const float* __restrict__ bv,
                    unsigned short* __restrict__ WQT, unsigned short* __restrict__ WKT,
                    unsigned short* __restrict__ WVT, unsigned short* __restrict__ WOT,
                    unsigned short* __restrict__ W1T, unsigned short* __restrict__ W2T,
                    float* __restrict__ bqkv,
                    const float* __restrict__ x, const float* __restrict__ g1,
                    const float* __restrict__ b1,
                    unsigned short* __restrict__ tn, unsigned short* __restrict__ xb)
{
    if (blockIdx.x < 3075) {
        int idx = blockIdx.x * 256 + threadIdx.x;
        if (idx < 262144) {                             // 4 square 256x256 mats
            int m = idx >> 16;
            int r = (idx >> 8) & 255;                   // k
            int c = idx & 255;                          // n
            const float* src = (m == 0) ? Wq : (m == 1) ? Wk : (m == 2) ? Wv : Wo;
            unsigned short* dst = (m == 0) ? WQT : (m == 1) ? WKT : (m == 2) ? WVT : WOT;
            float sc = (m == 0) ? ATT_SCALE : 1.0f;
            dst[c * 256 + r] = f2b(src[r * 256 + c] * sc);
        } else if (idx < 524288) {                      // W1: 256 x 1024
            int i = idx - 262144;
            int r = i >> 10, c = i & 1023;
            W1T[c * 256 + r] = f2b(W1[r * 1024 + c]);
        } else if (idx < 786432) {                      // W2: 1024 x 256
            int i = idx - 524288;
            int r = i >> 8, c = i & 255;
            W2T[c * 1024 + r] = f2b(W2[r * 256 + c]);
        } else {                                        // [bq*s|bk|bv] (768)
            int i = idx - 786432;
            if (i < 768)
                bqkv[i] = (i < 256) ? bq[i] * ATT_SCALE
                        : (i < 512) ? bk[i - 256] : bv[i - 512];
        }
    } else {
        const int row  = (blockIdx.x - 3075) * 4 + (threadIdx.x >> 6);
        const int lane = threadIdx.x & 63;
        float4 v = ((const float4*)(x + (size_t)row * C))[lane];
        float s = v.x + v.y + v.z + v.w;
        #pragma unroll
        for (int m = 32; m >= 1; m >>= 1) s += __shfl_xor(s, m);
        const float mean = s * (1.0f / 256.0f);
        const float d0 = v.x - mean, d1 = v.y - mean, d2 = v.z - mean, d3 = v.w - mean;
        float s2 = d0 * d0 + d1 * d1 + d2 * d2 + d3 * d3;
        #pragma unroll
        for (int m = 32; m >= 1; m >>= 1) s2 += __shfl_xor(s2, m);
        const float rstd = rsqrtf(s2 * (1.0f / 256.0f) + 1e-5f);
        float4 gg = ((const float4*)g1)[lane];
        float4 bb = ((const float4*)b1)[lane];
        ushort4 o = { f2b(d0 * rstd * gg.x + bb.x), f2b(d1 * rstd * gg.y + bb.y),
                      f2b(d2 * rstd * gg.z + bb.z), f2b(d3 * rstd * gg.w + bb.w) };
        ((ushort4*)(tn + (size_t)row * C))[lane] = o;
        ushort4 xo = { f2b(v.x), f2b(v.y), f2b(v.z), f2b(v.w) };
        ((ushort4*)(xb + (size_t)row * C))[lane] = xo;
    }
}

// ---------------------------------------------------------------- LN2
__global__ __launch_bounds__(256)
void ln_kernel(const float* __restrict__ X, const float* __restrict__ g,
               const float* __restrict__ bta, unsigned short* __restrict__ OUT)
{
    const int row  = blockIdx.x * 4 + (threadIdx.x >> 6);
    const int lane = threadIdx.x & 63;
    float4 v = ((const float4*)(X + (size_t)row * C))[lane];
    float s = v.x + v.y + v.z + v.w;
    #pragma unroll
    for (int m = 32; m >= 1; m >>= 1) s += __shfl_xor(s, m);
    const float mean = s * (1.0f / 256.0f);
    const float d0 = v.x - mean, d1 = v.y - mean, d2 = v.z - mean, d3 = v.w - mean;
    float s2 = d0 * d0 + d1 * d1 + d2 * d2 + d3 * d3;
    #pragma unroll
    for (int m = 32; m >= 1; m >>= 1) s2 += __shfl_xor(s2, m);
    const float rstd = rsqrtf(s2 * (1.0f / 256.0f) + 1e-5f);
    float4 gg = ((const float4*)g)[lane];
    float4 bb = ((const float4*)bta)[lane];
    ushort4 o = { f2b(d0 * rstd * gg.x + bb.x), f2b(d1 * rstd * gg.y + bb.y),
                  f2b(d2 * rstd * gg.z + bb.z), f2b(d3 * rstd * gg.w + bb.w) };
    ((ushort4*)(OUT + (size_t)row * C))[lane] = o;
}

// ---------------------------------------------------------------- GEMM core
// 64x64 tile, 128 threads (2 waves): wave w = rows [32w,32w+32), all 64 cols.
// B panel (64 cols x 256-K chunk) lives in 128 VGPRs, loaded from global (L2).
// A staged in LDS (XOR-swizzled, rule #21) and each A fragment read ONCE,
// reused across 4 n-MFMAs -> minimal LDS traffic. K=256: single barrier.
// K=1024: 4 chunks, chunk-granular double buffer.
// LDS layout: elem(row, c16) = row*256 + (c16 ^ (row&7))*8   (c16 = k/8, 0..31)
// MODE 0: out bf16; MODE 1: out bf16 = gelu; MODE 2: out f32 = acc+bias+res.
template<int K, int MODE, int NBUF>
DEV void gemm_body(const unsigned short* __restrict__ A, int m0,
                   const unsigned short* __restrict__ BT, int n0,
                   const float* __restrict__ bias,
                   const float* __restrict__ res, void* __restrict__ outp,
                   int ldo, unsigned short (&As)[NBUF][64 * 256])
{
    constexpr int NC = K / 256;
    const int tid  = threadIdx.x;
    const int lane = tid & 63, wid = tid >> 6;
    const int lr = lane & 15, lk = lane >> 4;

    // ---- stage chunk c of A into buffer b (32KB via 16 gload16/thread)
    auto STAGE = [&](int c, int b) {
        #pragma unroll
        for (int i = 0; i < 16; ++i) {
            const int row  = i * 4 + (tid >> 5);
            const int schk = (tid & 31) ^ (row & 7);
            gload16(A + (size_t)(m0 + row) * K + c * 256 + schk * 8,
                    &As[b][i * 1024 + tid * 8]);
        }
    };

    bf16x8 breg[4][8];
    auto LOADB = [&](int c) {
        #pragma unroll
        for (int n = 0; n < 4; ++n)
            #pragma unroll
            for (int ks = 0; ks < 8; ++ks)
                breg[n][ks] = *reinterpret_cast<const bf16x8*>(
                    BT + (size_t)(n0 + n * 16 + lr) * K + c * 256 + ks * 32 + lk * 8);
    };

    f32x4 acc[2][4] = {};

    STAGE(0, 0);
    LOADB(0);
    __syncthreads();

    #pragma unroll
    for (int c = 0; c < NC; ++c) {
        if (c + 1 < NC) STAGE(c + 1, (c + 1) & (NBUF - 1));
        if (c > 0) LOADB(c);
        const unsigned short* as = As[c & (NBUF - 1)];
        #pragma unroll
        for (int ks = 0; ks < 8; ++ks) {
            const int c16 = (ks * 4 + lk) ^ (lr & 7);
            bf16x8 a0 = *reinterpret_cast<const bf16x8*>(
                &as[(wid * 32 + lr) * 256 + c16 * 8]);
            bf16x8 a1 = *reinterpret_cast<const bf16x8*>(
                &as[(wid * 32 + 16 + lr) * 256 + c16 * 8]);
            #pragma unroll
            for (int n = 0; n < 4; ++n) {
                acc[0][n] = __builtin_amdgcn_mfma_f32_16x16x32_bf16(a0, breg[n][ks], acc[0][n], 0, 0, 0);
                acc[1][n] = __builtin_amdgcn_mfma_f32_16x16x32_bf16(a1, breg[n][ks], acc[1][n], 0, 0, 0);
            }
        }
        if (c + 1 < NC) __syncthreads();
    }

    #pragma unroll
    for (int n = 0; n < 4; ++n) {
        const int col  = n0 + n * 16 + lr;
        const float bcol = bias[col];
        #pragma unroll
        for (int m = 0; m < 2; ++m) {
            #pragma unroll
            for (int r = 0; r < 4; ++r) {
                const int row = m0 + wid * 32 + m * 16 + lk * 4 + r;
                float v = acc[m][n][r] + bcol;
                if (MODE == 0) {
                    ((unsigned short*)outp)[(size_t)row * ldo + col] = f2b(v);
                } else if (MODE == 1) {
                    ((unsigned short*)outp)[(size_t)row * ldo + col] = f2b(gelu_f(v));
                } else {
                    v += res[(size_t)row * ldo + col];
                    ((float*)outp)[(size_t)row * ldo + col] = v;
                }
            }
        }
    }
}

// Fused Q/K/V GEMM: N=768 packed output, A = tn for Q cols, xb for K/V cols.
__global__ __launch_bounds__(128)
void qkv_kernel(const unsigned short* __restrict__ tn,
                const unsigned short* __restrict__ xb,
                const unsigned short* __restrict__ WT,    // [768][256]
                const float* __restrict__ bqkv,           // [768]
                unsigned short* __restrict__ QKV)         // [8192][768]
{
    __shared__ unsigned short As[1][64 * 256];
    const int n0 = blockIdx.y * 64;
    const unsigned short* A = (n0 < 256) ? tn : xb;
    gemm_body<256, 0, 1>(A, blockIdx.x * 64, WT, n0, bqkv, nullptr, QKV, 768, As);
}

template<int K, int MODE>
__global__ __launch_bounds__(128)
void gemm_kernel(const unsigned short* __restrict__ A,
                 const unsigned short* __restrict__ BT,
                 const float* __restrict__ bias,
                 const float* __restrict__ res,
                 void* __restrict__ outp, int ldo)
{
    __shared__ unsigned short As[(K > 256) ? 2 : 1][64 * 256];
    gemm_body<K, MODE, (K > 256) ? 2 : 1>(A, blockIdx.x * 64, BT, blockIdx.y * 64,
                                          bias, res, outp, ldo, As);
}

// ---------------------------------------------------------------- attention
// 4 voxels per 256-thread block; each wave owns one voxel (wave-uniform masks).
// Thread = 4 contiguous channels of one head: lane l -> head l>>3, chans (l&7)*4.
// QKV layout: [NROW][768] bf16: Q (pre-scaled) 0..255, K 256..511, V 512..767.
__global__ __launch_bounds__(256)
void attn_kernel(const unsigned short* __restrict__ QKV,
                 unsigned short* __restrict__ AO)
{
    const int vox = blockIdx.x * 4 + (threadIdx.x >> 6);
    const int l   = threadIdx.x & 63;
    const int b = vox >> 12, d = (vox >> 8) & 15, h = (vox >> 4) & 15, w = vox & 15;
    const int ch = (l >> 3) * 32 + (l & 7) * 4;     // head*32 + lane-in-head*4

    ushort4 q4 = *reinterpret_cast<const ushort4*>(&QKV[(size_t)vox * 768 + ch]);
    const float q0 = b2f(q4.x), q1 = b2f(q4.y), q2 = b2f(q4.z), q3 = b2f(q4.w);

    float sc[27];
    int   nrow[27];
    #pragma unroll
    for (int kk = 0; kk < 27; ++kk) {
        const int di = kk / 9 - 1, hi = (kk / 3) % 3 - 1, wi = kk % 3 - 1;
        int nd = d + di, nh = h + hi, nw = w + wi;
        bool valid = (kk != 13) && ((unsigned)nd < 16u) && ((unsigned)nh < 16u) && ((unsigned)nw < 16u);
        if (valid) {
            int r = (b << 12) + (nd << 8) + (nh << 4) + nw;
            nrow[kk] = r;
            ushort4 k4 = *reinterpret_cast<const ushort4*>(&QKV[(size_t)r * 768 + 256 + ch]);
            float s = q0 * b2f(k4.x) + q1 * b2f(k4.y) + q2 * b2f(k4.z) + q3 * b2f(k4.w);
            s += __shfl_xor(s, 4);
            s += __shfl_xor(s, 2);
            s += __shfl_xor(s, 1);
            sc[kk] = s;
        } else {
            sc[kk] = -INFINITY;
            nrow[kk] = -1;
        }
    }

    float mx = -INFINITY;
    #pragma unroll
    for (int kk = 0; kk < 27; ++kk) mx = fmaxf(mx, sc[kk]);
    float sum = 0.0f;
    #pragma unroll
    for (int kk = 0; kk < 27; ++kk) { float p = __expf(sc[kk] - mx); sc[kk] = p; sum += p; }
    const float inv = 1.0f / sum;

    float a0 = 0.f, a1 = 0.f, a2 = 0.f, a3 = 0.f;
    #pragma unroll
    for (int kk = 0; kk < 27; ++kk) {
        if (nrow[kk] >= 0) {
            ushort4 v4 = *reinterpret_cast<const ushort4*>(&QKV[(size_t)nrow[kk] * 768 + 512 + ch]);
            const float p = sc[kk];
            a0 += p * b2f(v4.x); a1 += p * b2f(v4.y);
            a2 += p * b2f(v4.z); a3 += p * b2f(v4.w);
        }
    }
    ushort4 o4 = { f2b(a0 * inv), f2b(a1 * inv), f2b(a2 * inv), f2b(a3 * inv) };
    *reinterpret_cast<ushort4*>(&AO[(size_t)vox * C + ch]) = o4;
}

// ---------------------------------------------------------------- launch
extern "C" void kernel_launch(void* const* d_in, const int* in_sizes, int n_in,
                              void* d_out, int out_size, void* d_ws, size_t ws_size,
                              hipStream_t stream)
{
    const float* x   = (const float*)d_in[0];
    const float* Wq  = (const float*)d_in[1];
    const float* bq  = (const float*)d_in[2];
    const float* Wk  = (const float*)d_in[3];
    const float* bk  = (const float*)d_in[4];
    const float* Wv  = (const float*)d_in[5];
    const float* bv  = (const float*)d_in[6];
    const float* Wo  = (const float*)d_in[7];
    const float* bo  = (const float*)d_in[8];
    const float* g1  = (const float*)d_in[9];
    const float* b1  = (const float*)d_in[10];
    const float* g2  = (const float*)d_in[11];
    const float* b2  = (const float*)d_in[12];
    const float* W1  = (const float*)d_in[13];
    const float* bf1 = (const float*)d_in[14];
    const float* W2  = (const float*)d_in[15];
    const float* bf2 = (const float*)d_in[16];

    char* ws = (char*)d_ws;
    size_t o = 0;
    unsigned short* WQT = (unsigned short*)(ws + o); o += (size_t)256 * 256 * 2;   // [768][256] with WKT/WVT
    unsigned short* WKT = (unsigned short*)(ws + o); o += (size_t)256 * 256 * 2;
    unsigned short* WVT = (unsigned short*)(ws + o); o += (size_t)256 * 256 * 2;
    unsigned short* WOT = (unsigned short*)(ws + o); o += (size_t)256 * 256 * 2;
    unsigned short* W1T = (unsigned short*)(ws + o); o += (size_t)256 * 1024 * 2;
    unsigned short* W2T = (unsigned short*)(ws + o); o += (size_t)1024 * 256 * 2;
    float*          bqkv= (float*)(ws + o);          o += (size_t)768 * 4;
    unsigned short* tn  = (unsigned short*)(ws + o); o += (size_t)NROW * C * 2;
    unsigned short* xb  = (unsigned short*)(ws + o); o += (size_t)NROW * C * 2;
    unsigned short* QKVb= (unsigned short*)(ws + o); o += (size_t)NROW * 768 * 2;
    unsigned short* AOb = (unsigned short*)(ws + o); o += (size_t)NROW * C * 2;
    float*          Tf  = (float*)(ws + o);          o += (size_t)NROW * C * 4;
    unsigned short* tn2 = (unsigned short*)(ws + o); o += (size_t)NROW * C * 2;
    unsigned short* Hb  = (unsigned short*)(ws + o); o += (size_t)NROW * F * 2;

    prep_ln_kernel<<<5123, 256, 0, stream>>>(Wq, Wk, Wv, Wo, W1, W2, bq, bk, bv,
                                             WQT, WKT, WVT, WOT, W1T, W2T, bqkv,
                                             x, g1, b1, tn, xb);

    qkv_kernel<<<dim3(NROW / 64, 12), 128, 0, stream>>>(tn, xb, WQT, bqkv, QKVb);

    attn_kernel<<<NROW / 4, 256, 0, stream>>>(QKVb, AOb);

    gemm_kernel<256, 2><<<dim3(NROW / 64, 4), 128, 0, stream>>>(AOb, WOT, bo, x, Tf, 256);

    ln_kernel<<<NROW / 4, 256, 0, stream>>>(Tf, g2, b2, tn2);

    gemm_kernel<256, 1><<<dim3(NROW / 64, 16), 128, 0, stream>>>(tn2, W1T, bf1, nullptr, Hb, 1024);

    gemm_kernel<1024, 2><<<dim3(NROW / 64, 4), 128, 0, stream>>>(Hb, W2T, bf2, Tf, (float*)d_out, 256);
}

// Round 6
// 92.228 us; speedup vs baseline: 1.3760x; 1.3760x over previous
//
#include <hip/hip_runtime.h>

typedef __bf16 bf16x8 __attribute__((ext_vector_type(8)));
typedef float f32x4 __attribute__((ext_vector_type(4)));

#define DEV static __device__ __forceinline__

DEV unsigned short f2b(float f){
    unsigned int u = __float_as_uint(f);
    u += 0x7fffu + ((u >> 16) & 1u);
    return (unsigned short)(u >> 16);
}
DEV float b2f(unsigned short h){ return __uint_as_float(((unsigned int)h) << 16); }
DEV float gelu_f(float x){ return 0.5f * x * (1.0f + erff(x * 0.7071067811865476f)); }

// async global->LDS, 16B per lane. LDS dest must be linear in lane order.
DEV void gload16(const unsigned short* g, unsigned short* l){
    __builtin_amdgcn_global_load_lds(
        (const __attribute__((address_space(1))) void*)g,
        (__attribute__((address_space(3))) void*)l, 16, 0, 0);
}

// ---------------------------------------------------------------- constants
static constexpr int NROW = 8192;   // B*D*H*W = 2*16*16*16
static constexpr int C    = 256;
static constexpr int F    = 1024;
static constexpr float ATT_SCALE = 0.17677669529663688f;   // 1/sqrt(32)

// ---------------------------------------------------------------- prep + LN1
// Blocks 0..191: LDS-tiled transpose+bf16 of the 6 weight mats (64x64 tiles,
// coalesced reads AND writes). Block 192: [bq*s|bk|bv]. Blocks 193+: LN1.
__global__ __launch_bounds__(256)
void prep_ln_kernel(const float* __restrict__ Wq, const float* __restrict__ Wk,
                    const float* __restrict__ Wv, const float* __restrict__ Wo,
                    const float* __restrict__ W1, const float* __restrict__ W2,
                    const float* __restrict__ bq, const float* __restrict__ bk,
                    const float* __restrict__ bv,
                    unsigned short* __restrict__ WQT, unsigned short* __restrict__ WKT,
                    unsigned short* __restrict__ WVT, unsigned short* __restrict__ WOT,
                    unsigned short* __restrict__ W1T, unsigned short* __restrict__ W2T,
                    float* __restrict__ bqkv,
                    const float* __restrict__ x, const float* __restrict__ g1,
                    const float* __restrict__ b1,
                    unsigned short* __restrict__ tn, unsigned short* __restrict__ xb)
{
    const int tid = threadIdx.x;
    if (blockIdx.x < 192) {
        __shared__ unsigned short T[64][66];
        const int t = blockIdx.x;
        const float* src; unsigned short* dst;
        int ldw, ldt, r0, c0; float sc = 1.0f;
        if (t < 64) {                       // 4 square 256x256 mats, 16 tiles each
            const int m = t >> 4, sub = t & 15;
            src = (m == 0) ? Wq : (m == 1) ? Wk : (m == 2) ? Wv : Wo;
            dst = (m == 0) ? WQT : (m == 1) ? WKT : (m == 2) ? WVT : WOT;
            if (m == 0) sc = ATT_SCALE;
            ldw = 256; ldt = 256;
            r0 = (sub >> 2) * 64; c0 = (sub & 3) * 64;
        } else if (t < 128) {               // W1: 256x1024 -> W1T [1024][256]
            const int sub = t - 64;
            src = W1; dst = W1T; ldw = 1024; ldt = 256;
            r0 = (sub >> 4) * 64; c0 = (sub & 15) * 64;
        } else {                            // W2: 1024x256 -> W2T [256][1024]
            const int sub = t - 128;
            src = W2; dst = W2T; ldw = 256; ldt = 1024;
            r0 = (sub >> 2) * 64; c0 = (sub & 3) * 64;
        }
        #pragma unroll
        for (int i = 0; i < 16; ++i) {
            const int rl = i * 4 + (tid >> 6), cl = tid & 63;
            T[rl][cl] = f2b(src[(size_t)(r0 + rl) * ldw + c0 + cl] * sc);
        }
        __syncthreads();
        #pragma unroll
        for (int j = 0; j < 16; ++j) {
            const int cl = j * 4 + (tid >> 6), rl = tid & 63;
            dst[(size_t)(c0 + cl) * ldt + r0 + rl] = T[rl][cl];
        }
    } else if (blockIdx.x == 192) {
        #pragma unroll
        for (int i = 0; i < 3; ++i) {
            const int v = i * 256 + tid;
            bqkv[v] = (v < 256) ? bq[v] * ATT_SCALE
                    : (v < 512) ? bk[v - 256] : bv[v - 512];
        }
    } else {
        const int row  = (blockIdx.x - 193) * 4 + (tid >> 6);
        const int lane = tid & 63;
        float4 v = ((const float4*)(x + (size_t)row * C))[lane];
        float s = v.x + v.y + v.z + v.w;
        #pragma unroll
        for (int m = 32; m >= 1; m >>= 1) s += __shfl_xor(s, m);
        const float mean = s * (1.0f / 256.0f);
        const float d0 = v.x - mean, d1 = v.y - mean, d2 = v.z - mean, d3 = v.w - mean;
        float s2 = d0 * d0 + d1 * d1 + d2 * d2 + d3 * d3;
        #pragma unroll
        for (int m = 32; m >= 1; m >>= 1) s2 += __shfl_xor(s2, m);
        const float rstd = rsqrtf(s2 * (1.0f / 256.0f) + 1e-5f);
        float4 gg = ((const float4*)g1)[lane];
        float4 bb = ((const float4*)b1)[lane];
        ushort4 o = { f2b(d0 * rstd * gg.x + bb.x), f2b(d1 * rstd * gg.y + bb.y),
                      f2b(d2 * rstd * gg.z + bb.z), f2b(d3 * rstd * gg.w + bb.w) };
        ((ushort4*)(tn + (size_t)row * C))[lane] = o;
        ushort4 xo = { f2b(v.x), f2b(v.y), f2b(v.z), f2b(v.w) };
        ((ushort4*)(xb + (size_t)row * C))[lane] = xo;
    }
}

// ---------------------------------------------------------------- LN2
__global__ __launch_bounds__(256)
void ln_kernel(const float* __restrict__ X, const float* __restrict__ g,
               const float* __restrict__ bta, unsigned short* __restrict__ OUT)
{
    const int row  = blockIdx.x * 4 + (threadIdx.x >> 6);
    const int lane = threadIdx.x & 63;
    float4 v = ((const float4*)(X + (size_t)row * C))[lane];
    float s = v.x + v.y + v.z + v.w;
    #pragma unroll
    for (int m = 32; m >= 1; m >>= 1) s += __shfl_xor(s, m);
    const float mean = s * (1.0f / 256.0f);
    const float d0 = v.x - mean, d1 = v.y - mean, d2 = v.z - mean, d3 = v.w - mean;
    float s2 = d0 * d0 + d1 * d1 + d2 * d2 + d3 * d3;
    #pragma unroll
    for (int m = 32; m >= 1; m >>= 1) s2 += __shfl_xor(s2, m);
    const float rstd = rsqrtf(s2 * (1.0f / 256.0f) + 1e-5f);
    float4 gg = ((const float4*)g)[lane];
    float4 bb = ((const float4*)bta)[lane];
    ushort4 o = { f2b(d0 * rstd * gg.x + bb.x), f2b(d1 * rstd * gg.y + bb.y),
                  f2b(d2 * rstd * gg.z + bb.z), f2b(d3 * rstd * gg.w + bb.w) };
    ((ushort4*)(OUT + (size_t)row * C))[lane] = o;
}

// ---------------------------------------------------------------- GEMM core
// Round-4 structure: 64x64 tile, BK=64, 256 threads (4 waves), double-buffered
// LDS via global_load_lds w16, XOR-swizzled (rule #21): linear gload dest +
// inverse-swizzled global source chunk + swizzled ds_read.
// LDS layout: byte(row, col16) = row*128 + (col16 ^ (row&7))*16.
// MODE 0: out bf16; MODE 1: out bf16 = gelu; MODE 2: out f32 = acc+bias+res.
template<int K, int MODE>
DEV void gemm_body(const unsigned short* __restrict__ A, int m0,
                   const unsigned short* __restrict__ BTt,
                   const float* __restrict__ biast,
                   const float* __restrict__ res, void* __restrict__ outp,
                   int ldo, int ocol0,
                   unsigned short (&As)[2][4096], unsigned short (&Bs)[2][4096])
{
    constexpr int BK = 64, NKT = K / BK;
    const int tid  = threadIdx.x;
    const int lane = tid & 63, wid = tid >> 6;
    const int srow = tid >> 3;                    // 0..31
    const int schk = (tid & 7) ^ (srow & 7);      // inverse-swizzled src chunk

    const unsigned short* Ag = A   + (size_t)(m0 + srow) * K + schk * 8;
    const unsigned short* Bg = BTt + (size_t)srow        * K + schk * 8;

    {
        unsigned short* Al = &As[0][tid * 8];
        unsigned short* Bl = &Bs[0][tid * 8];
        gload16(Ag, Al);            gload16(Ag + 32 * K, Al + 2048);
        gload16(Bg, Bl);            gload16(Bg + 32 * K, Bl + 2048);
    }
    __syncthreads();

    f32x4 acc[4] = {};
    const int lr = lane & 15, lk = lane >> 4;
    const int sw = lr & 7;                        // row&7 for all fragment rows

    for (int kt = 0; kt < NKT; ++kt) {
        if (kt + 1 < NKT) {
            const int nb = (kt + 1) & 1;
            unsigned short* Al = &As[nb][tid * 8];
            unsigned short* Bl = &Bs[nb][tid * 8];
            gload16(Ag + (kt + 1) * BK, Al);
            gload16(Ag + 32 * K + (kt + 1) * BK, Al + 2048);
            gload16(Bg + (kt + 1) * BK, Bl);
            gload16(Bg + 32 * K + (kt + 1) * BK, Bl + 2048);
        }
        const unsigned short* as = As[kt & 1];
        const unsigned short* bs = Bs[kt & 1];
        #pragma unroll
        for (int s = 0; s < 2; ++s) {
            const int c16 = (s * 4 + lk) ^ sw;
            bf16x8 bfr = *reinterpret_cast<const bf16x8*>(&bs[(wid * 16 + lr) * 64 + c16 * 8]);
            #pragma unroll
            for (int m = 0; m < 4; ++m) {
                bf16x8 afr = *reinterpret_cast<const bf16x8*>(&as[(m * 16 + lr) * 64 + c16 * 8]);
                acc[m] = __builtin_amdgcn_mfma_f32_16x16x32_bf16(afr, bfr, acc[m], 0, 0, 0);
            }
        }
        if (kt + 1 < NKT) __syncthreads();
    }

    const int col  = ocol0 + wid * 16 + lr;
    const float bcol = biast[wid * 16 + lr];
    #pragma unroll
    for (int m = 0; m < 4; ++m) {
        #pragma unroll
        for (int r = 0; r < 4; ++r) {
            const int row = m0 + m * 16 + lk * 4 + r;
            float v = acc[m][r] + bcol;
            if (MODE == 0) {
                ((unsigned short*)outp)[(size_t)row * ldo + col] = f2b(v);
            } else if (MODE == 1) {
                ((unsigned short*)outp)[(size_t)row * ldo + col] = f2b(gelu_f(v));
            } else {
                v += res[(size_t)row * ldo + col];
                ((float*)outp)[(size_t)row * ldo + col] = v;
            }
        }
    }
}

// XCD-swizzled 1D-grid tile map, column-fastest: all NC column-blocks of a
// row-panel land on the SAME XCD -> A-panel read once per XCD L2 (T1).
// Requires nwg % 8 == 0 (true for all our grids).
template<int NC>
DEV void tile_map(int& m0, int& n0){
    const int nwg = gridDim.x;
    const int lin = blockIdx.x;
    const int tile = (lin & 7) * (nwg >> 3) + (lin >> 3);
    m0 = (tile / NC) * 64;
    n0 = (tile % NC) * 64;
}

// Fused Q/K/V GEMM: N=768 packed output, A = tn for Q cols, xb for K/V cols.
__global__ __launch_bounds__(256)
void qkv_kernel(const unsigned short* __restrict__ tn,
                const unsigned short* __restrict__ xb,
                const unsigned short* __restrict__ WT,    // [768][256]
                const float* __restrict__ bqkv,           // [768]
                unsigned short* __restrict__ QKV)         // [8192][768]
{
    __shared__ unsigned short As[2][4096], Bs[2][4096];
    int m0, n0; tile_map<12>(m0, n0);
    const unsigned short* A = (n0 < 256) ? tn : xb;
    gemm_body<256, 0>(A, m0, WT + (size_t)n0 * 256,
                      bqkv + n0, nullptr, QKV, 768, n0, As, Bs);
}

template<int K, int MODE, int NC>
__global__ __launch_bounds__(256)
void gemm_kernel(const unsigned short* __restrict__ A,
                 const unsigned short* __restrict__ BT,
                 const float* __restrict__ bias,
                 const float* __restrict__ res,
                 void* __restrict__ outp, int ldo)
{
    __shared__ unsigned short As[2][4096], Bs[2][4096];
    int m0, n0; tile_map<NC>(m0, n0);
    gemm_body<K, MODE>(A, m0, BT + (size_t)n0 * K,
                       bias + n0, res, outp, ldo, n0, As, Bs);
}

// ---------------------------------------------------------------- attention
// 4 voxels per 256-thread block; each wave owns one voxel (wave-uniform masks).
// Thread = 4 contiguous channels of one head: lane l -> head l>>3, chans (l&7)*4.
// QKV layout: [NROW][768] bf16: Q (pre-scaled) 0..255, K 256..511, V 512..767.
__global__ __launch_bounds__(256)
void attn_kernel(const unsigned short* __restrict__ QKV,
                 unsigned short* __restrict__ AO)
{
    const int vox = blockIdx.x * 4 + (threadIdx.x >> 6);
    const int l   = threadIdx.x & 63;
    const int b = vox >> 12, d = (vox >> 8) & 15, h = (vox >> 4) & 15, w = vox & 15;
    const int ch = (l >> 3) * 32 + (l & 7) * 4;     // head*32 + lane-in-head*4

    ushort4 q4 = *reinterpret_cast<const ushort4*>(&QKV[(size_t)vox * 768 + ch]);
    const float q0 = b2f(q4.x), q1 = b2f(q4.y), q2 = b2f(q4.z), q3 = b2f(q4.w);

    float sc[27];
    int   nrow[27];
    #pragma unroll
    for (int kk = 0; kk < 27; ++kk) {
        const int di = kk / 9 - 1, hi = (kk / 3) % 3 - 1, wi = kk % 3 - 1;
        int nd = d + di, nh = h + hi, nw = w + wi;
        bool valid = (kk != 13) && ((unsigned)nd < 16u) && ((unsigned)nh < 16u) && ((unsigned)nw < 16u);
        if (valid) {
            int r = (b << 12) + (nd << 8) + (nh << 4) + nw;
            nrow[kk] = r;
            ushort4 k4 = *reinterpret_cast<const ushort4*>(&QKV[(size_t)r * 768 + 256 + ch]);
            float s = q0 * b2f(k4.x) + q1 * b2f(k4.y) + q2 * b2f(k4.z) + q3 * b2f(k4.w);
            s += __shfl_xor(s, 4);
            s += __shfl_xor(s, 2);
            s += __shfl_xor(s, 1);
            sc[kk] = s;
        } else {
            sc[kk] = -INFINITY;
            nrow[kk] = -1;
        }
    }

    float mx = -INFINITY;
    #pragma unroll
    for (int kk = 0; kk < 27; ++kk) mx = fmaxf(mx, sc[kk]);
    float sum = 0.0f;
    #pragma unroll
    for (int kk = 0; kk < 27; ++kk) { float p = __expf(sc[kk] - mx); sc[kk] = p; sum += p; }
    const float inv = 1.0f / sum;

    float a0 = 0.f, a1 = 0.f, a2 = 0.f, a3 = 0.f;
    #pragma unroll
    for (int kk = 0; kk < 27; ++kk) {
        if (nrow[kk] >= 0) {
            ushort4 v4 = *reinterpret_cast<const ushort4*>(&QKV[(size_t)nrow[kk] * 768 + 512 + ch]);
            const float p = sc[kk];
            a0 += p * b2f(v4.x); a1 += p * b2f(v4.y);
            a2 += p * b2f(v4.z); a3 += p * b2f(v4.w);
        }
    }
    ushort4 o4 = { f2b(a0 * inv), f2b(a1 * inv), f2b(a2 * inv), f2b(a3 * inv) };
    *reinterpret_cast<ushort4*>(&AO[(size_t)vox * C + ch]) = o4;
}

// ---------------------------------------------------------------- launch
extern "C" void kernel_launch(void* const* d_in, const int* in_sizes, int n_in,
                              void* d_out, int out_size, void* d_ws, size_t ws_size,
                              hipStream_t stream)
{
    const float* x   = (const float*)d_in[0];
    const float* Wq  = (const float*)d_in[1];
    const float* bq  = (const float*)d_in[2];
    const float* Wk  = (const float*)d_in[3];
    const float* bk  = (const float*)d_in[4];
    const float* Wv  = (const float*)d_in[5];
    const float* bv  = (const float*)d_in[6];
    const float* Wo  = (const float*)d_in[7];
    const float* bo  = (const float*)d_in[8];
    const float* g1  = (const float*)d_in[9];
    const float* b1  = (const float*)d_in[10];
    const float* g2  = (const float*)d_in[11];
    const float* b2  = (const float*)d_in[12];
    const float* W1  = (const float*)d_in[13];
    const float* bf1 = (const float*)d_in[14];
    const float* W2  = (const float*)d_in[15];
    const float* bf2 = (const float*)d_in[16];

    char* ws = (char*)d_ws;
    size_t o = 0;
    unsigned short* WQT = (unsigned short*)(ws + o); o += (size_t)256 * 256 * 2;   // [768][256] with WKT/WVT
    unsigned short* WKT = (unsigned short*)(ws + o); o += (size_t)256 * 256 * 2;
    unsigned short* WVT = (unsigned short*)(ws + o); o += (size_t)256 * 256 * 2;
    unsigned short* WOT = (unsigned short*)(ws + o); o += (size_t)256 * 256 * 2;
    unsigned short* W1T = (unsigned short*)(ws + o); o += (size_t)256 * 1024 * 2;
    unsigned short* W2T = (unsigned short*)(ws + o); o += (size_t)1024 * 256 * 2;
    float*          bqkv= (float*)(ws + o);          o += (size_t)768 * 4;
    unsigned short* tn  = (unsigned short*)(ws + o); o += (size_t)NROW * C * 2;
    unsigned short* xb  = (unsigned short*)(ws + o); o += (size_t)NROW * C * 2;
    unsigned short* QKVb= (unsigned short*)(ws + o); o += (size_t)NROW * 768 * 2;
    unsigned short* AOb = (unsigned short*)(ws + o); o += (size_t)NROW * C * 2;
    float*          Tf  = (float*)(ws + o);          o += (size_t)NROW * C * 4;
    unsigned short* tn2 = (unsigned short*)(ws + o); o += (size_t)NROW * C * 2;
    unsigned short* Hb  = (unsigned short*)(ws + o); o += (size_t)NROW * F * 2;

    prep_ln_kernel<<<193 + NROW / 4, 256, 0, stream>>>(Wq, Wk, Wv, Wo, W1, W2, bq, bk, bv,
                                                       WQT, WKT, WVT, WOT, W1T, W2T, bqkv,
                                                       x, g1, b1, tn, xb);

    qkv_kernel<<<(NROW / 64) * 12, 256, 0, stream>>>(tn, xb, WQT, bqkv, QKVb);

    attn_kernel<<<NROW / 4, 256, 0, stream>>>(QKVb, AOb);

    gemm_kernel<256, 2, 4><<<(NROW / 64) * 4, 256, 0, stream>>>(AOb, WOT, bo, x, Tf, 256);

    ln_kernel<<<NROW / 4, 256, 0, stream>>>(Tf, g2, b2, tn2);

    gemm_kernel<256, 1, 16><<<(NROW / 64) * 16, 256, 0, stream>>>(tn2, W1T, bf1, nullptr, Hb, 1024);

    gemm_kernel<1024, 2, 4><<<(NROW / 64) * 4, 256, 0, stream>>>(Hb, W2T, bf2, Tf, (float*)d_out, 256);
}